// Round 2
// baseline (436.021 us; speedup 1.0000x reference)
//
#include <hip/hip_runtime.h>
#include <math.h>
#include <float.h>

#define Bz 16
#define Cc 64
#define Hh 64
#define Ww 64
#define Kn 1024
#define HW 4096
#define CHW 262144
#define NTOK 65536
#define NELEM 4194304

// ---------------- kernel A: per-channel std (ddof=1), clipped ----------------
// (kept bit-identical to the round-1 version that validated)
__global__ __launch_bounds__(256) void k_std(const float* __restrict__ z,
                                             float* __restrict__ stdv) {
  int c = blockIdx.x;
  int tid = threadIdx.x;
  double s = 0.0, s2 = 0.0;
  const float* base = z + c * HW;
  for (int i = tid; i < NTOK; i += 256) {
    int b = i >> 12;
    int off = i & 4095;
    float v = base[(size_t)b * CHW + off];
    s += (double)v;
    s2 += (double)v * (double)v;
  }
  for (int o = 32; o > 0; o >>= 1) {
    s += __shfl_down(s, o, 64);
    s2 += __shfl_down(s2, o, 64);
  }
  __shared__ double rs[4], rs2[4];
  int wv = tid >> 6, ln = tid & 63;
  if (ln == 0) { rs[wv] = s; rs2[wv] = s2; }
  __syncthreads();
  if (tid == 0) {
    double S = rs[0] + rs[1] + rs[2] + rs[3];
    double S2 = rs2[0] + rs2[1] + rs2[2] + rs2[3];
    const double N = (double)NTOK;
    double var = (S2 - S * S / N) / (N - 1.0);
    float sd = (float)sqrt(var);
    stdv[c] = fmaxf(sd, 1e-5f);
  }
}

// ---------------- main kernel: LDS-tiled argmin over K + epilogue ----------------
// Block = 4 waves, 64 tokens (lane = w). Codebook staged in 128-row LDS tiles;
// wave wv handles rows [wv*32, wv*32+32) of each tile (ascending k per wave).
// Hot loop: uniform ds_read_b128 (broadcast) + v_fma_f32 into 2 accumulators.
// No ws reads via scalar path, no atomics, fully deterministic.
__global__ __launch_bounds__(256, 2) void k_vq(
    const float* __restrict__ z_e, const float* __restrict__ emb,
    const float* __restrict__ stdv,
    float* __restrict__ out_zq, float* __restrict__ out_idx,
    float* __restrict__ loss_part) {
  __shared__ float et[128 * 64];   // 32 KB codebook tile
  __shared__ float eet[128];       // row norms for the tile
  __shared__ float s_std[64];
  __shared__ float s_bd[4][64];
  __shared__ int   s_bk[4][64];
  __shared__ int   s_k[64];
  __shared__ float s_red[4];

  int tid = threadIdx.x;
  int lane = tid & 63;
  int wv = tid >> 6;
  int bh = blockIdx.x;
  int b = bh >> 6, h = bh & 63;

  if (tid < 64) s_std[tid] = stdv[tid];   // per-lane vector load (coherent path)
  __syncthreads();

  // this lane's normalized token vector in registers (IEEE div; same as round-1)
  const float* zbase = z_e + (size_t)b * CHW + h * Ww + lane;
  float zr[64];
  float zz = 0.f;
  #pragma unroll
  for (int c = 0; c < 64; ++c) {
    float v = zbase[(size_t)c * HW] / s_std[c];
    zr[c] = v;
    zz = fmaf(v, v, zz);
  }

  float bestd = FLT_MAX;
  int bestk = 0;

  for (int tile = 0; tile < 8; ++tile) {
    __syncthreads();   // previous tile's readers done before overwrite
    {  // stage 128 rows (8192 floats) cooperatively, coalesced float4
      const float4* g4 = (const float4*)(emb + (tile << 13));
      float4* l4 = (float4*)et;
      #pragma unroll
      for (int j = 0; j < 8; ++j) l4[j * 256 + tid] = g4[j * 256 + tid];
    }
    if (tid < 128) {   // row norms, sequential fmaf (matches round-1 k_ee order)
      const float* er = emb + (((tile << 7) + tid) << 6);
      float s = 0.f;
      #pragma unroll
      for (int c = 0; c < 64; ++c) s = fmaf(er[c], er[c], s);
      eet[tid] = s;
    }
    __syncthreads();

    #pragma unroll 4
    for (int rr = 0; rr < 32; rr += 2) {
      int r = (wv << 5) + rr;            // local row in tile (wave-uniform)
      int k0 = (tile << 7) + r;          // global codebook index
      const float4* e40 = (const float4*)&et[r << 6];
      const float4* e41 = (const float4*)&et[(r + 1) << 6];
      float d0 = 0.f, d1 = 0.f;
      #pragma unroll
      for (int c4 = 0; c4 < 16; ++c4) {
        float4 a = e40[c4];
        float4 b4 = e41[c4];
        d0 = fmaf(a.x, zr[c4 * 4 + 0], d0);
        d0 = fmaf(a.y, zr[c4 * 4 + 1], d0);
        d0 = fmaf(a.z, zr[c4 * 4 + 2], d0);
        d0 = fmaf(a.w, zr[c4 * 4 + 3], d0);
        d1 = fmaf(b4.x, zr[c4 * 4 + 0], d1);
        d1 = fmaf(b4.y, zr[c4 * 4 + 1], d1);
        d1 = fmaf(b4.z, zr[c4 * 4 + 2], d1);
        d1 = fmaf(b4.w, zr[c4 * 4 + 3], d1);
      }
      float dd0 = (zz - 2.0f * d0) + eet[r];
      float dd1 = (zz - 2.0f * d1) + eet[r + 1];
      if (dd0 < bestd) { bestd = dd0; bestk = k0; }
      if (dd1 < bestd) { bestd = dd1; bestk = k0 + 1; }
    }
  }

  s_bd[wv][lane] = bestd;
  s_bk[wv][lane] = bestk;
  __syncthreads();

  // combine 4 waves; k-chunks interleave, so tie must pick the smaller k
  if (tid < 64) {
    float bd = s_bd[0][tid];
    int bk = s_bk[0][tid];
    #pragma unroll
    for (int w = 1; w < 4; ++w) {
      float d2 = s_bd[w][tid];
      int k2 = s_bk[w][tid];
      if (d2 < bd || (d2 == bd && k2 < bk)) { bd = d2; bk = k2; }
    }
    s_k[tid] = bk;
    out_idx[bh * 64 + tid] = (float)bk;
  }
  __syncthreads();

  // epilogue: z_q_st + per-block loss partial (z recomputed bit-identically)
  int bk = s_k[lane];
  const float* eq = emb + (bk << 6);
  float lsum = 0.f;
  const float* zb2 = z_e + (size_t)b * CHW + h * Ww + lane;
  float* ob = out_zq + (size_t)b * CHW + h * Ww + lane;
  #pragma unroll
  for (int j = 0; j < 16; ++j) {
    int c = (wv << 4) + j;               // wave-uniform channel -> coalesced
    float zv = zb2[(size_t)c * HW] / s_std[c];
    float e = eq[c];
    float diff = zv - e;
    lsum = fmaf(diff, diff, lsum);
    ob[(size_t)c * HW] = zv + (e - zv);
  }
  for (int o = 32; o > 0; o >>= 1) lsum += __shfl_down(lsum, o, 64);
  if (lane == 0) s_red[wv] = lsum;
  __syncthreads();
  if (tid == 0) loss_part[bh] = s_red[0] + s_red[1] + s_red[2] + s_red[3];
}

// ---------------- finalize: vq_loss + perplexity (histogram from indices) ----------------
__global__ __launch_bounds__(256) void k_fin(const float* __restrict__ loss_part,
                                             const float* __restrict__ out_idx,
                                             float* __restrict__ out_scalars) {
  __shared__ int hist[1024];
  int tid = threadIdx.x;
  for (int i = tid; i < 1024; i += 256) hist[i] = 0;
  __syncthreads();
  const float2* idx2 = (const float2*)out_idx;   // base is 8B-aligned
  for (int i = tid; i < NTOK / 2; i += 256) {
    float2 v = idx2[i];
    atomicAdd(&hist[(int)v.x], 1);
    atomicAdd(&hist[(int)v.y], 1);
  }
  __syncthreads();
  double ls = 0.0, hs = 0.0;
  for (int i = tid; i < 1024; i += 256) {
    ls += (double)loss_part[i];
    float p = (float)hist[i] * (1.0f / 65536.0f);
    float lg = logf(fmaxf(p, 1e-10f));
    hs += (double)(p * lg);
  }
  for (int o = 32; o > 0; o >>= 1) {
    ls += __shfl_down(ls, o, 64);
    hs += __shfl_down(hs, o, 64);
  }
  __shared__ double rl[4], rh[4];
  int wv = tid >> 6, ln = tid & 63;
  if (ln == 0) { rl[wv] = ls; rh[wv] = hs; }
  __syncthreads();
  if (tid == 0) {
    double L = rl[0] + rl[1] + rl[2] + rl[3];
    double Hn = rh[0] + rh[1] + rh[2] + rh[3];
    float m = (float)(L / (double)NELEM);
    out_scalars[0] = 0.25f * m + m;
    out_scalars[1] = expf((float)(-Hn));
  }
}

extern "C" void kernel_launch(void* const* d_in, const int* in_sizes, int n_in,
                              void* d_out, int out_size, void* d_ws, size_t ws_size,
                              hipStream_t stream) {
  const float* z_e = (const float*)d_in[0];
  const float* emb = (const float*)d_in[1];
  float* ws = (float*)d_ws;
  float* loss_part = ws;          // 1024 floats
  float* stdv = ws + 1024;        // 64 floats  (total ws use: 4.4 KB)

  float* out = (float*)d_out;
  float* out_zq = out;            // 4194304
  float* out_scalars = out + NELEM;        // vq_loss, perplexity
  float* out_idx = out + NELEM + 2;        // 65536 indices as float

  k_std<<<Cc, 256, 0, stream>>>(z_e, stdv);
  k_vq<<<Bz * Hh, 256, 0, stream>>>(z_e, emb, stdv, out_zq, out_idx, loss_part);
  k_fin<<<1, 256, 0, stream>>>(loss_part, out_idx, out_scalars);
}

// Round 3
// 286.340 us; speedup vs baseline: 1.5227x; 1.5227x over previous
//
#include <hip/hip_runtime.h>
#include <math.h>
#include <float.h>

#define Bz 16
#define Cc 64
#define Hh 64
#define Ww 64
#define Kn 1024
#define HW 4096
#define CHW 262144
#define NTOK 65536
#define NELEM 4194304

// ---------------- kernel A: per-channel std (ddof=1), clipped ----------------
// bit-identical to the round-2 version that validated
__global__ __launch_bounds__(256) void k_std(const float* __restrict__ z,
                                             float* __restrict__ stdv) {
  int c = blockIdx.x;
  int tid = threadIdx.x;
  double s = 0.0, s2 = 0.0;
  const float* base = z + c * HW;
  for (int i = tid; i < NTOK; i += 256) {
    int b = i >> 12;
    int off = i & 4095;
    float v = base[(size_t)b * CHW + off];
    s += (double)v;
    s2 += (double)v * (double)v;
  }
  for (int o = 32; o > 0; o >>= 1) {
    s += __shfl_down(s, o, 64);
    s2 += __shfl_down(s2, o, 64);
  }
  __shared__ double rs[4], rs2[4];
  int wv = tid >> 6, ln = tid & 63;
  if (ln == 0) { rs[wv] = s; rs2[wv] = s2; }
  __syncthreads();
  if (tid == 0) {
    double S = rs[0] + rs[1] + rs[2] + rs[3];
    double S2 = rs2[0] + rs2[1] + rs2[2] + rs2[3];
    const double N = (double)NTOK;
    double var = (S2 - S * S / N) / (N - 1.0);
    float sd = (float)sqrt(var);
    stdv[c] = fmaxf(sd, 1e-5f);
  }
}

// ---------------- main kernel: T=2 tokens/lane, LDS-tiled argmin ----------------
// Block = 4 waves, 128 tokens (2 h-rows; lane = w, two tokens per lane).
// One codebook-row LDS read now feeds 2 tokens' FMAs -> b128 count halved
// vs round 2 (16.8M -> 8.4M). Distance arithmetic bit-identical to round 2.
__global__ __launch_bounds__(256, 3) void k_vq(
    const float* __restrict__ z_e, const float* __restrict__ emb,
    const float* __restrict__ stdv,
    float* __restrict__ out_zq, float* __restrict__ out_idx,
    float* __restrict__ loss_part) {
  __shared__ float et[128 * 64];   // 32 KB codebook tile
  __shared__ float eet[128];       // row norms for the tile
  __shared__ float s_std[64];
  __shared__ float s_bd[4][128];
  __shared__ int   s_bk[4][128];
  __shared__ int   s_k[128];
  __shared__ float s_red[4];

  int tid = threadIdx.x;
  int lane = tid & 63;
  int wv = tid >> 6;
  int blk = blockIdx.x;            // 512 blocks: b = blk>>5, h0 = (blk&31)*2
  int b = blk >> 5, h0 = (blk & 31) << 1;

  if (tid < 64) s_std[tid] = stdv[tid];
  __syncthreads();

  // two tokens per lane: (b, h0, lane) and (b, h0+1, lane)
  const float* zb0 = z_e + (size_t)b * CHW + h0 * Ww + lane;
  const float* zb1 = zb0 + Ww;
  float zr0[64], zr1[64];
  float zz0 = 0.f, zz1 = 0.f;
  #pragma unroll
  for (int c = 0; c < 64; ++c) {
    float sd = s_std[c];
    float v0 = zb0[(size_t)c * HW] / sd;
    float v1 = zb1[(size_t)c * HW] / sd;
    zr0[c] = v0; zz0 = fmaf(v0, v0, zz0);
    zr1[c] = v1; zz1 = fmaf(v1, v1, zz1);
  }

  float bd0 = FLT_MAX, bd1 = FLT_MAX;
  int bk0 = 0, bk1 = 0;

  for (int tile = 0; tile < 8; ++tile) {
    __syncthreads();
    {  // stage 128 rows cooperatively, coalesced float4
      const float4* g4 = (const float4*)(emb + (tile << 13));
      float4* l4 = (float4*)et;
      #pragma unroll
      for (int j = 0; j < 8; ++j) l4[j * 256 + tid] = g4[j * 256 + tid];
    }
    if (tid < 128) {   // row norms, sequential fmaf (bit-exact vs round 2)
      const float* er = emb + (((tile << 7) + tid) << 6);
      float s = 0.f;
      #pragma unroll
      for (int c = 0; c < 64; ++c) s = fmaf(er[c], er[c], s);
      eet[tid] = s;
    }
    __syncthreads();

    #pragma unroll 1
    for (int rr = 0; rr < 32; rr += 2) {
      int r = (wv << 5) + rr;
      int k0 = (tile << 7) + r;
      const float4* e40 = (const float4*)&et[r << 6];
      const float4* e41 = (const float4*)&et[(r + 1) << 6];
      float d00 = 0.f, d10 = 0.f;   // token0 x {row r, row r+1}
      float d01 = 0.f, d11 = 0.f;   // token1 x {row r, row r+1}
      #pragma unroll
      for (int c4 = 0; c4 < 16; ++c4) {
        float4 a = e40[c4];
        float4 b4 = e41[c4];
        float z00 = zr0[c4 * 4 + 0], z01 = zr0[c4 * 4 + 1];
        float z02 = zr0[c4 * 4 + 2], z03 = zr0[c4 * 4 + 3];
        float z10 = zr1[c4 * 4 + 0], z11 = zr1[c4 * 4 + 1];
        float z12 = zr1[c4 * 4 + 2], z13 = zr1[c4 * 4 + 3];
        d00 = fmaf(a.x, z00, d00); d00 = fmaf(a.y, z01, d00);
        d00 = fmaf(a.z, z02, d00); d00 = fmaf(a.w, z03, d00);
        d10 = fmaf(b4.x, z00, d10); d10 = fmaf(b4.y, z01, d10);
        d10 = fmaf(b4.z, z02, d10); d10 = fmaf(b4.w, z03, d10);
        d01 = fmaf(a.x, z10, d01); d01 = fmaf(a.y, z11, d01);
        d01 = fmaf(a.z, z12, d01); d01 = fmaf(a.w, z13, d01);
        d11 = fmaf(b4.x, z10, d11); d11 = fmaf(b4.y, z11, d11);
        d11 = fmaf(b4.z, z12, d11); d11 = fmaf(b4.w, z13, d11);
      }
      float ee0 = eet[r], ee1 = eet[r + 1];
      float dd00 = (zz0 - 2.0f * d00) + ee0;
      float dd10 = (zz0 - 2.0f * d10) + ee1;
      float dd01 = (zz1 - 2.0f * d01) + ee0;
      float dd11 = (zz1 - 2.0f * d11) + ee1;
      if (dd00 < bd0) { bd0 = dd00; bk0 = k0; }
      if (dd10 < bd0) { bd0 = dd10; bk0 = k0 + 1; }
      if (dd01 < bd1) { bd1 = dd01; bk1 = k0; }
      if (dd11 < bd1) { bd1 = dd11; bk1 = k0 + 1; }
    }
  }

  s_bd[wv][lane] = bd0;       s_bk[wv][lane] = bk0;
  s_bd[wv][64 + lane] = bd1;  s_bk[wv][64 + lane] = bk1;
  __syncthreads();

  // combine 4 waves; chunks interleave -> tie picks smaller k
  if (tid < 128) {
    float bd = s_bd[0][tid];
    int bk = s_bk[0][tid];
    #pragma unroll
    for (int w = 1; w < 4; ++w) {
      float d2 = s_bd[w][tid];
      int k2 = s_bk[w][tid];
      if (d2 < bd || (d2 == bd && k2 < bk)) { bd = d2; bk = k2; }
    }
    s_k[tid] = bk;
    out_idx[blk * 128 + tid] = (float)bk;
  }
  __syncthreads();

  // epilogue: z_q_st + loss partial (z recomputed bit-identically)
  int q0 = s_k[lane], q1 = s_k[64 + lane];
  const float* eq0 = emb + (q0 << 6);
  const float* eq1 = emb + (q1 << 6);
  float lsum = 0.f;
  float* ob0 = out_zq + (size_t)b * CHW + h0 * Ww + lane;
  float* ob1 = ob0 + Ww;
  #pragma unroll
  for (int j = 0; j < 16; ++j) {
    int c = (wv << 4) + j;               // wave-uniform channel -> coalesced
    float sd = s_std[c];
    float zv0 = zb0[(size_t)c * HW] / sd;
    float e0 = eq0[c];
    float df0 = zv0 - e0;
    lsum = fmaf(df0, df0, lsum);
    ob0[(size_t)c * HW] = zv0 + (e0 - zv0);
    float zv1 = zb1[(size_t)c * HW] / sd;
    float e1 = eq1[c];
    float df1 = zv1 - e1;
    lsum = fmaf(df1, df1, lsum);
    ob1[(size_t)c * HW] = zv1 + (e1 - zv1);
  }
  for (int o = 32; o > 0; o >>= 1) lsum += __shfl_down(lsum, o, 64);
  if (lane == 0) s_red[wv] = lsum;
  __syncthreads();
  if (tid == 0) loss_part[blk] = s_red[0] + s_red[1] + s_red[2] + s_red[3];
}

// ---------------- finalize: vq_loss + perplexity (1024 threads) ----------------
__global__ __launch_bounds__(1024) void k_fin(const float* __restrict__ loss_part,
                                              const float* __restrict__ out_idx,
                                              float* __restrict__ out_scalars) {
  __shared__ int hist[1024];
  int tid = threadIdx.x;
  if (tid < 1024) hist[tid] = 0;
  __syncthreads();
  const float2* idx2 = (const float2*)out_idx;   // 8B-aligned base
  for (int i = tid; i < NTOK / 2; i += 1024) {
    float2 v = idx2[i];
    atomicAdd(&hist[(int)v.x], 1);
    atomicAdd(&hist[(int)v.y], 1);
  }
  __syncthreads();
  double ls = 0.0, hs = 0.0;
  if (tid < 512) ls = (double)loss_part[tid];
  {
    float p = (float)hist[tid] * (1.0f / 65536.0f);
    float lg = logf(fmaxf(p, 1e-10f));
    hs = (double)(p * lg);
  }
  for (int o = 32; o > 0; o >>= 1) {
    ls += __shfl_down(ls, o, 64);
    hs += __shfl_down(hs, o, 64);
  }
  __shared__ double rl[16], rh[16];
  int wv = tid >> 6, ln = tid & 63;
  if (ln == 0) { rl[wv] = ls; rh[wv] = hs; }
  __syncthreads();
  if (tid == 0) {
    double L = 0.0, Hn = 0.0;
    #pragma unroll
    for (int w = 0; w < 16; ++w) { L += rl[w]; Hn += rh[w]; }
    float m = (float)(L / (double)NELEM);
    out_scalars[0] = 0.25f * m + m;
    out_scalars[1] = expf((float)(-Hn));
  }
}

extern "C" void kernel_launch(void* const* d_in, const int* in_sizes, int n_in,
                              void* d_out, int out_size, void* d_ws, size_t ws_size,
                              hipStream_t stream) {
  const float* z_e = (const float*)d_in[0];
  const float* emb = (const float*)d_in[1];
  float* ws = (float*)d_ws;
  float* loss_part = ws;          // 512 floats
  float* stdv = ws + 512;         // 64 floats (total ws use: 2.3 KB)

  float* out = (float*)d_out;
  float* out_zq = out;            // 4194304
  float* out_scalars = out + NELEM;        // vq_loss, perplexity
  float* out_idx = out + NELEM + 2;        // 65536 indices as float

  k_std<<<Cc, 256, 0, stream>>>(z_e, stdv);
  k_vq<<<512, 256, 0, stream>>>(z_e, emb, stdv, out_zq, out_idx, loss_part);
  k_fin<<<1, 1024, 0, stream>>>(loss_part, out_idx, out_scalars);
}

// Round 4
// 209.493 us; speedup vs baseline: 2.0813x; 1.3668x over previous
//
#include <hip/hip_runtime.h>
#include <math.h>
#include <float.h>

#define HW 4096
#define CHW 262144
#define NTOK 65536
#define NELEM 4194304

// ws float offsets
#define WS_LOSS 0        // 512 floats
#define WS_STD  512      // 64
#define WS_EE   576      // 1024
#define WS_ETG  1600     // 65536 : codebook transposed [64 c][1024 k]
#define WS_HIST 67136    // 16384 ints (16 partial hists)

// ---------------- per-channel std (ddof=1), 1024 threads, float4 ----------------
__global__ __launch_bounds__(1024) void k_std(const float* __restrict__ z,
                                              float* __restrict__ stdv) {
  int c = blockIdx.x;
  int tid = threadIdx.x;
  double s = 0.0, s2 = 0.0;
  const float* base = z + c * HW;
  #pragma unroll 4
  for (int jj = 0; jj < 16; ++jj) {
    int f = tid + (jj << 10);
    int b = f >> 10, off4 = f & 1023;
    float4 v = *(const float4*)(base + (size_t)b * CHW + (off4 << 2));
    s  += (double)v.x + (double)v.y + (double)v.z + (double)v.w;
    s2 += (double)v.x * v.x + (double)v.y * v.y + (double)v.z * v.z + (double)v.w * v.w;
  }
  for (int o = 32; o > 0; o >>= 1) {
    s += __shfl_down(s, o, 64);
    s2 += __shfl_down(s2, o, 64);
  }
  __shared__ double rs[16], rs2[16];
  int wv = tid >> 6, ln = tid & 63;
  if (ln == 0) { rs[wv] = s; rs2[wv] = s2; }
  __syncthreads();
  if (tid == 0) {
    double S = 0.0, S2 = 0.0;
    #pragma unroll
    for (int w = 0; w < 16; ++w) { S += rs[w]; S2 += rs2[w]; }
    const double N = (double)NTOK;
    double var = (S2 - S * S / N) / (N - 1.0);
    float sd = (float)sqrt(var);
    stdv[c] = fmaxf(sd, 1e-5f);
  }
}

// ---------------- transpose codebook to [c][k] + row norms ----------------
__global__ __launch_bounds__(256) void k_tr(const float* __restrict__ emb,
                                            float* __restrict__ etg,
                                            float* __restrict__ eeg) {
  __shared__ float T[64][65];
  int tid = threadIdx.x;
  int k0 = blockIdx.x << 6;       // 16 blocks x 64 codes
  #pragma unroll
  for (int jj = 0; jj < 4; ++jj) {
    int f = tid + (jj << 8);
    int code = f >> 4, c4 = f & 15;
    float4 v = *(const float4*)(emb + (size_t)((k0 + code) << 6) + (c4 << 2));
    T[code][(c4 << 2) + 0] = v.x;
    T[code][(c4 << 2) + 1] = v.y;
    T[code][(c4 << 2) + 2] = v.z;
    T[code][(c4 << 2) + 3] = v.w;
  }
  __syncthreads();
  #pragma unroll
  for (int jj = 0; jj < 4; ++jj) {
    int f = tid + (jj << 8);
    int c = f >> 4, k4 = f & 15;
    float4 v = make_float4(T[(k4 << 2) + 0][c], T[(k4 << 2) + 1][c],
                           T[(k4 << 2) + 2][c], T[(k4 << 2) + 3][c]);
    *(float4*)(etg + c * 1024 + k0 + (k4 << 2)) = v;
  }
  if (tid < 64) {   // sequential fmaf — bit-identical to round-3 eet
    const float* er = emb + (size_t)((k0 + tid) << 6);
    float s = 0.f;
    #pragma unroll
    for (int c = 0; c < 64; ++c) s = fmaf(er[c], er[c], s);
    eeg[k0 + tid] = s;
  }
}

// ---------------- main kernel: 128x128 register-tile argmin ----------------
// Block = 4 waves as 2x2 (token-half x code-half). Wave tile 64 tok x 64 codes,
// lane = 8x8 grid, 8 tok x 8 code accumulators/lane. Per c-step: 4 ds_read_b128
// feed 64 MACs (16 FMA/b128, 2x round-3). z staged [c][tok] once (global layout
// is already c-major); codes staged per 128-tile from transposed etg, prefetched
// into regs across the barrier. Dot/zz/ee numerics bit-identical to round 3.
__global__ __launch_bounds__(256, 2) void k_vq(
    const float* __restrict__ z_e, const float* __restrict__ emb,
    const float* __restrict__ stdv, const float* __restrict__ eeg,
    const float* __restrict__ etg,
    float* __restrict__ out_zq, float* __restrict__ out_idx,
    float* __restrict__ loss_part) {
  __shared__ float zt[64 * 128];   // [c][tok]
  __shared__ float et[64 * 128];   // [c][code]
  __shared__ float eet[128];
  __shared__ float zzt[128];
  __shared__ float sstd[64];
  __shared__ float rbd[2 * 128];
  __shared__ int   rbk[2 * 128];
  __shared__ int   skf[128];
  __shared__ float sred[4];

  int tid = threadIdx.x;
  int lane = tid & 63;
  int wv = tid >> 6;
  int blk = blockIdx.x;           // 512 blocks
  int b = blk >> 5;
  int s0 = (blk & 31) << 7;       // 128 contiguous spatial positions

  if (tid < 64) sstd[tid] = stdv[tid];
  __syncthreads();

  // stage zt (normalized), prefetch code tile 0 + its norms
  const float* zbase = z_e + (size_t)b * CHW + s0;
  float4 pf[8];
  float eet0 = 0.f;
  #pragma unroll
  for (int jj = 0; jj < 8; ++jj) {
    int f = tid + (jj << 8);
    int c = f >> 5, t4 = f & 31;
    float4 v = *(const float4*)(zbase + (size_t)c * HW + (t4 << 2));
    float sd = sstd[c];
    v.x /= sd; v.y /= sd; v.z /= sd; v.w /= sd;
    *(float4*)&zt[(c << 7) + (t4 << 2)] = v;
  }
  #pragma unroll
  for (int jj = 0; jj < 8; ++jj) {
    int f = tid + (jj << 8);
    int c = f >> 5, k4 = f & 31;
    pf[jj] = *(const float4*)(etg + c * 1024 + (k4 << 2));
  }
  if (tid < 128) eet0 = eeg[tid];
  __syncthreads();   // zt ready

  // zz pass (ascending-c fmaf, bit-identical) + write code tile 0
  if (tid < 128) {
    float a = 0.f;
    #pragma unroll
    for (int c = 0; c < 64; ++c) { float v = zt[(c << 7) + tid]; a = fmaf(v, v, a); }
    zzt[tid] = a;
    eet[tid] = eet0;
  }
  #pragma unroll
  for (int jj = 0; jj < 8; ++jj) {
    int f = tid + (jj << 8);
    int c = f >> 5, k4 = f & 31;
    *(float4*)&et[(c << 7) + (k4 << 2)] = pf[jj];
  }
  __syncthreads();   // et0 + zzt ready

  int i8 = (lane >> 3) << 3;
  int j8 = (lane & 7) << 3;
  int wt = wv >> 1, wc = wv & 1;
  int toff = wt * 64 + i8;
  int koff = wc * 64 + j8;

  float zzr[8];
  #pragma unroll
  for (int ii = 0; ii < 8; ++ii) zzr[ii] = zzt[toff + ii];

  float bd[8]; int bk[8];
  #pragma unroll
  for (int ii = 0; ii < 8; ++ii) { bd[ii] = FLT_MAX; bk[ii] = 0; }

  const float4* ztp = (const float4*)&zt[toff];
  const float4* etp = (const float4*)&et[koff];

  for (int tile = 0; tile < 8; ++tile) {
    float eer[8];
    #pragma unroll
    for (int jj = 0; jj < 8; ++jj) eer[jj] = eet[koff + jj];

    float4 npf[8]; float neet = 0.f;
    if (tile < 7) {   // prefetch next tile into regs (stays in flight over compute)
      const float* src = etg + ((tile + 1) << 7);
      #pragma unroll
      for (int jj = 0; jj < 8; ++jj) {
        int f = tid + (jj << 8);
        int c = f >> 5, k4 = f & 31;
        npf[jj] = *(const float4*)(src + c * 1024 + (k4 << 2));
      }
      if (tid < 128) neet = eeg[((tile + 1) << 7) + tid];
    }

    float2 acc[8][4];
    #pragma unroll
    for (int ii = 0; ii < 8; ++ii)
      #pragma unroll
      for (int jj = 0; jj < 4; ++jj) acc[ii][jj] = make_float2(0.f, 0.f);

    #pragma unroll 8
    for (int c = 0; c < 64; ++c) {
      float4 za = ztp[c << 5], zb4 = ztp[(c << 5) + 1];
      float4 ea = etp[c << 5], eb4 = etp[(c << 5) + 1];
      float zv[8] = {za.x, za.y, za.z, za.w, zb4.x, zb4.y, zb4.z, zb4.w};
      float ev[8] = {ea.x, ea.y, ea.z, ea.w, eb4.x, eb4.y, eb4.z, eb4.w};
      #pragma unroll
      for (int ii = 0; ii < 8; ++ii) {
        float z1 = zv[ii];
        #pragma unroll
        for (int jj = 0; jj < 4; ++jj) {
          acc[ii][jj].x = fmaf(z1, ev[2 * jj], acc[ii][jj].x);
          acc[ii][jj].y = fmaf(z1, ev[2 * jj + 1], acc[ii][jj].y);
        }
      }
    }

    int kb = (tile << 7) + koff;   // ascending k within lane across jj and tiles
    #pragma unroll
    for (int ii = 0; ii < 8; ++ii) {
      float z2 = zzr[ii];
      #pragma unroll
      for (int jj = 0; jj < 4; ++jj) {
        float dd0 = (z2 - 2.0f * acc[ii][jj].x) + eer[2 * jj];
        float dd1 = (z2 - 2.0f * acc[ii][jj].y) + eer[2 * jj + 1];
        if (dd0 < bd[ii]) { bd[ii] = dd0; bk[ii] = kb + 2 * jj; }
        if (dd1 < bd[ii]) { bd[ii] = dd1; bk[ii] = kb + 2 * jj + 1; }
      }
    }

    __syncthreads();   // everyone done reading et/eet
    if (tile < 7) {
      #pragma unroll
      for (int jj = 0; jj < 8; ++jj) {
        int f = tid + (jj << 8);
        int c = f >> 5, k4 = f & 31;
        *(float4*)&et[(c << 7) + (k4 << 2)] = npf[jj];
      }
      if (tid < 128) eet[tid] = neet;
      __syncthreads(); // next tile ready
    }
  }

  // reduce over the 8 code-groups (lane bits 0..2), tie -> smaller k
  #pragma unroll
  for (int m = 1; m <= 4; m <<= 1) {
    #pragma unroll
    for (int ii = 0; ii < 8; ++ii) {
      float od = __shfl_xor(bd[ii], m, 64);
      int   ok = __shfl_xor(bk[ii], m, 64);
      if (od < bd[ii] || (od == bd[ii] && ok < bk[ii])) { bd[ii] = od; bk[ii] = ok; }
    }
  }
  if ((lane & 7) == 0) {
    #pragma unroll
    for (int ii = 0; ii < 8; ++ii) {
      rbd[wc * 128 + toff + ii] = bd[ii];
      rbk[wc * 128 + toff + ii] = bk[ii];
    }
  }
  __syncthreads();

  if (tid < 128) {
    float d0 = rbd[tid];       int k0 = rbk[tid];
    float d1 = rbd[128 + tid]; int k1 = rbk[128 + tid];
    int kb2 = (d1 < d0 || (d1 == d0 && k1 < k0)) ? k1 : k0;
    skf[tid] = kb2;
    out_idx[(blk << 7) + tid] = (float)kb2;
  }
  __syncthreads();

  // epilogue: z from LDS (bit-same), e gathered from emb, coalesced stores
  int t = tid & 127;
  int ch = tid >> 7;
  int kq = skf[t];
  const float* eq = emb + (size_t)(kq << 6) + (ch << 5);
  float lsum = 0.f;
  float* ob = out_zq + (size_t)b * CHW + s0 + t;
  #pragma unroll
  for (int jj = 0; jj < 32; ++jj) {
    int c = (ch << 5) + jj;
    float zv = zt[(c << 7) + t];
    float e = eq[jj];
    float df = zv - e;
    lsum = fmaf(df, df, lsum);
    ob[(size_t)c * HW] = zv + (e - zv);
  }
  for (int o = 32; o > 0; o >>= 1) lsum += __shfl_down(lsum, o, 64);
  if (lane == 0) sred[wv] = lsum;
  __syncthreads();
  if (tid == 0) loss_part[blk] = sred[0] + sred[1] + sred[2] + sred[3];
}

// ---------------- partial histograms (16 blocks x 4096 tokens) ----------------
__global__ __launch_bounds__(256) void k_hist(const float* __restrict__ out_idx,
                                              int* __restrict__ histg) {
  __shared__ int hist[1024];
  int tid = threadIdx.x;
  int blk = blockIdx.x;
  #pragma unroll
  for (int jj = 0; jj < 4; ++jj) hist[tid + (jj << 8)] = 0;
  __syncthreads();
  const float2* idx2 = (const float2*)(out_idx + (blk << 12));  // 8B-aligned
  #pragma unroll
  for (int jj = 0; jj < 8; ++jj) {
    float2 v = idx2[tid + (jj << 8)];
    atomicAdd(&hist[(int)v.x], 1);
    atomicAdd(&hist[(int)v.y], 1);
  }
  __syncthreads();
  #pragma unroll
  for (int jj = 0; jj < 4; ++jj) {
    int i = tid + (jj << 8);
    histg[(blk << 10) + i] = hist[i];
  }
}

// ---------------- finalize ----------------
__global__ __launch_bounds__(1024) void k_fin(const float* __restrict__ loss_part,
                                              const int* __restrict__ histg,
                                              float* __restrict__ out_scalars) {
  int tid = threadIdx.x;
  int cnt = 0;
  #pragma unroll
  for (int bI = 0; bI < 16; ++bI) cnt += histg[(bI << 10) + tid];
  double ls = 0.0;
  if (tid < 512) ls = (double)loss_part[tid];
  float p = (float)cnt * (1.0f / 65536.0f);
  float lg = logf(fmaxf(p, 1e-10f));
  double hs = (double)(p * lg);
  for (int o = 32; o > 0; o >>= 1) {
    ls += __shfl_down(ls, o, 64);
    hs += __shfl_down(hs, o, 64);
  }
  __shared__ double rl[16], rh[16];
  int wv = tid >> 6, ln = tid & 63;
  if (ln == 0) { rl[wv] = ls; rh[wv] = hs; }
  __syncthreads();
  if (tid == 0) {
    double L = 0.0, Hn = 0.0;
    #pragma unroll
    for (int w = 0; w < 16; ++w) { L += rl[w]; Hn += rh[w]; }
    float m = (float)(L / (double)NELEM);
    out_scalars[0] = 0.25f * m + m;
    out_scalars[1] = expf((float)(-Hn));
  }
}

extern "C" void kernel_launch(void* const* d_in, const int* in_sizes, int n_in,
                              void* d_out, int out_size, void* d_ws, size_t ws_size,
                              hipStream_t stream) {
  const float* z_e = (const float*)d_in[0];
  const float* emb = (const float*)d_in[1];
  float* ws = (float*)d_ws;
  float* loss_part = ws + WS_LOSS;
  float* stdv = ws + WS_STD;
  float* eeg = ws + WS_EE;
  float* etg = ws + WS_ETG;
  int* histg = (int*)(ws + WS_HIST);   // total ws use ~334 KB

  float* out = (float*)d_out;
  float* out_zq = out;                  // 4194304
  float* out_scalars = out + NELEM;     // vq_loss, perplexity
  float* out_idx = out + NELEM + 2;     // 65536 indices as float

  k_std<<<64, 1024, 0, stream>>>(z_e, stdv);
  k_tr<<<16, 256, 0, stream>>>(emb, etg, eeg);
  k_vq<<<512, 256, 0, stream>>>(z_e, emb, stdv, eeg, etg, out_zq, out_idx, loss_part);
  k_hist<<<16, 256, 0, stream>>>(out_idx, histg);
  k_fin<<<1, 1024, 0, stream>>>(loss_part, histg, out_scalars);
}

// Round 5
// 206.595 us; speedup vs baseline: 2.1105x; 1.0140x over previous
//
#include <hip/hip_runtime.h>
#include <math.h>
#include <float.h>

#define HW 4096
#define CHW 262144
#define NTOK 65536
#define NELEM 4194304

// ws float offsets
#define WS_LOSS 0        // 512 floats
#define WS_STD  512      // 64
#define WS_EE   576      // 1024
#define WS_ETG  1600     // 65536 : codebook transposed [64 c][1024 k]

__device__ __forceinline__ void gload_lds16(const float* g, float* l) {
  __builtin_amdgcn_global_load_lds(
      (const __attribute__((address_space(1))) unsigned int*)g,
      (__attribute__((address_space(3))) unsigned int*)l, 16, 0, 0);
}

// ---------------- k_pre: blocks 0..63 = per-channel std, 64..79 = transpose ----------------
__global__ __launch_bounds__(1024) void k_pre(const float* __restrict__ z,
                                              const float* __restrict__ emb,
                                              float* __restrict__ stdv,
                                              float* __restrict__ etg,
                                              float* __restrict__ eeg) {
  __shared__ double rs[16], rs2[16];
  __shared__ float T[64][65];
  int tid = threadIdx.x;
  int blk = blockIdx.x;
  if (blk < 64) {
    // per-channel std (ddof=1) — bit-identical to validated round-4 k_std
    int c = blk;
    double s = 0.0, s2 = 0.0;
    const float* base = z + c * HW;
    #pragma unroll 4
    for (int jj = 0; jj < 16; ++jj) {
      int f = tid + (jj << 10);
      int b = f >> 10, off4 = f & 1023;
      float4 v = *(const float4*)(base + (size_t)b * CHW + (off4 << 2));
      s  += (double)v.x + (double)v.y + (double)v.z + (double)v.w;
      s2 += (double)v.x * v.x + (double)v.y * v.y + (double)v.z * v.z + (double)v.w * v.w;
    }
    for (int o = 32; o > 0; o >>= 1) {
      s += __shfl_down(s, o, 64);
      s2 += __shfl_down(s2, o, 64);
    }
    int wv = tid >> 6, ln = tid & 63;
    if (ln == 0) { rs[wv] = s; rs2[wv] = s2; }
    __syncthreads();
    if (tid == 0) {
      double S = 0.0, S2 = 0.0;
      #pragma unroll
      for (int w = 0; w < 16; ++w) { S += rs[w]; S2 += rs2[w]; }
      const double N = (double)NTOK;
      double var = (S2 - S * S / N) / (N - 1.0);
      float sd = (float)sqrt(var);
      stdv[c] = fmaxf(sd, 1e-5f);
    }
  } else {
    // transpose 64 codebook rows to [c][k] + row norms (norms bit-identical)
    int k0 = (blk - 64) << 6;
    {
      int code = tid >> 4, c4 = tid & 15;
      float4 v = *(const float4*)(emb + (size_t)((k0 + code) << 6) + (c4 << 2));
      T[code][(c4 << 2) + 0] = v.x;
      T[code][(c4 << 2) + 1] = v.y;
      T[code][(c4 << 2) + 2] = v.z;
      T[code][(c4 << 2) + 3] = v.w;
    }
    __syncthreads();
    {
      int c = tid >> 4, k4 = tid & 15;
      float4 v = make_float4(T[(k4 << 2) + 0][c], T[(k4 << 2) + 1][c],
                             T[(k4 << 2) + 2][c], T[(k4 << 2) + 3][c]);
      *(float4*)(etg + c * 1024 + k0 + (k4 << 2)) = v;
    }
    if (tid < 64) {
      const float* er = emb + (size_t)((k0 + tid) << 6);
      float s = 0.f;
      #pragma unroll
      for (int c = 0; c < 64; ++c) s = fmaf(er[c], er[c], s);
      eeg[k0 + tid] = s;
    }
  }
}

// ---------------- main kernel: 128 tok x 64-code tiles, acc 8x4/lane ----------------
// Block = 4 waves as 2x2 (token-half x 32-code-half). Lane: 8 tok x 4 codes
// (acc = 8 float4 = 32 VGPRs -> no spill; live set ~90). Code tile (16 KB)
// staged via global_load_lds (zero staging VGPRs). LDS 52.7 KB -> 3 blocks/CU.
// Dot order / distance expr / tie-breaks bit-identical to validated rounds.
#define FMA8(ii, zc) \
  acc[ii].x = fmaf(zc, ea.x, acc[ii].x); \
  acc[ii].y = fmaf(zc, ea.y, acc[ii].y); \
  acc[ii].z = fmaf(zc, ea.z, acc[ii].z); \
  acc[ii].w = fmaf(zc, ea.w, acc[ii].w);

__global__ __launch_bounds__(256, 3) void k_vq(
    const float* __restrict__ z_e, const float* __restrict__ emb,
    const float* __restrict__ stdv, const float* __restrict__ eeg,
    const float* __restrict__ etg,
    float* __restrict__ out_zq, float* __restrict__ out_idx,
    float* __restrict__ loss_part) {
  __shared__ float zt[64 * 128];   // 32 KB [c][tok]
  __shared__ float et[64 * 64];    // 16 KB [c][code] current tile
  __shared__ float eetS[64];
  __shared__ float zzt[128];
  __shared__ float sstd[64];
  __shared__ float rbd[2 * 128];
  __shared__ int   rbk[2 * 128];
  __shared__ int   skf[128];
  __shared__ float sred[4];

  int tid = threadIdx.x;
  int lane = tid & 63;
  int wv = tid >> 6;
  int blk = blockIdx.x;           // 512 blocks
  int b = blk >> 5;
  int s0 = (blk & 31) << 7;       // 128 contiguous spatial positions

  if (tid < 64) sstd[tid] = stdv[tid];
  __syncthreads();

  // stage zt (normalized, IEEE div — bit-identical)
  const float* zbase = z_e + (size_t)b * CHW + s0;
  #pragma unroll
  for (int jj = 0; jj < 8; ++jj) {
    int f = tid + (jj << 8);
    int c = f >> 5, t4 = f & 31;
    float4 v = *(const float4*)(zbase + (size_t)c * HW + (t4 << 2));
    float sd = sstd[c];
    v.x /= sd; v.y /= sd; v.z /= sd; v.w /= sd;
    *(float4*)&zt[(c << 7) + (t4 << 2)] = v;
  }
  __syncthreads();

  // zz (ascending-c fmaf, bit-identical)
  if (tid < 128) {
    float a = 0.f;
    #pragma unroll
    for (int c = 0; c < 64; ++c) { float v = zt[(c << 7) + tid]; a = fmaf(v, v, a); }
    zzt[tid] = a;
  }
  __syncthreads();

  int toff = ((wv >> 1) << 6) + ((lane >> 3) << 3);   // 8-token group base
  int kloc = ((wv & 1) << 5) + ((lane & 7) << 2);     // 4-code group in tile
  int tq4 = toff >> 2;
  int kq4 = kloc >> 2;

  float zzr[8];
  #pragma unroll
  for (int ii = 0; ii < 8; ++ii) zzr[ii] = zzt[toff + ii];

  float bd[8]; int bk[8];
  #pragma unroll
  for (int ii = 0; ii < 8; ++ii) { bd[ii] = FLT_MAX; bk[ii] = 0; }

  // DMA source/dest bases for this thread (4 x 16B per tile)
  int c0 = tid >> 4;
  int k16 = (tid & 15) << 2;
  const float* gbase = etg + c0 * 1024 + k16;
  float* lbase = et + (c0 << 6) + k16;

  for (int tile = 0; tile < 16; ++tile) {
    __syncthreads();   // previous tile's readers done
    {
      const float* gsrc = gbase + (tile << 6);
      #pragma unroll
      for (int jj = 0; jj < 4; ++jj)
        gload_lds16(gsrc + jj * 16384, lbase + jj * 1024);
      if (tid < 64) eetS[tid] = eeg[(tile << 6) + tid];
    }
    __syncthreads();   // DMA + eet drained (compiler inserts vmcnt/lgkm wait)

    float4 acc[8];
    #pragma unroll
    for (int ii = 0; ii < 8; ++ii) acc[ii] = make_float4(0.f, 0.f, 0.f, 0.f);

    #pragma unroll 8
    for (int c = 0; c < 64; ++c) {
      float4 ea = ((const float4*)et)[(c << 4) + kq4];
      float4 za = ((const float4*)zt)[(c << 5) + tq4];
      float4 zb = ((const float4*)zt)[(c << 5) + tq4 + 1];
      FMA8(0, za.x) FMA8(1, za.y) FMA8(2, za.z) FMA8(3, za.w)
      FMA8(4, zb.x) FMA8(5, zb.y) FMA8(6, zb.z) FMA8(7, zb.w)
    }

    int kb = (tile << 6) + kloc;   // ascending k across tiles and within lane
    float e0 = eetS[kloc], e1 = eetS[kloc + 1];
    float e2 = eetS[kloc + 2], e3 = eetS[kloc + 3];
    #pragma unroll
    for (int ii = 0; ii < 8; ++ii) {
      float z2 = zzr[ii];
      float dd0 = (z2 - 2.0f * acc[ii].x) + e0;
      float dd1 = (z2 - 2.0f * acc[ii].y) + e1;
      float dd2 = (z2 - 2.0f * acc[ii].z) + e2;
      float dd3 = (z2 - 2.0f * acc[ii].w) + e3;
      if (dd0 < bd[ii]) { bd[ii] = dd0; bk[ii] = kb; }
      if (dd1 < bd[ii]) { bd[ii] = dd1; bk[ii] = kb + 1; }
      if (dd2 < bd[ii]) { bd[ii] = dd2; bk[ii] = kb + 2; }
      if (dd3 < bd[ii]) { bd[ii] = dd3; bk[ii] = kb + 3; }
    }
  }

  // reduce over the 8 code-groups (lane bits 0..2), tie -> smaller k
  #pragma unroll
  for (int m = 1; m <= 4; m <<= 1) {
    #pragma unroll
    for (int ii = 0; ii < 8; ++ii) {
      float od = __shfl_xor(bd[ii], m, 64);
      int   ok = __shfl_xor(bk[ii], m, 64);
      if (od < bd[ii] || (od == bd[ii] && ok < bk[ii])) { bd[ii] = od; bk[ii] = ok; }
    }
  }
  if ((lane & 7) == 0) {
    int base = ((wv & 1) << 7) + toff;
    #pragma unroll
    for (int ii = 0; ii < 8; ++ii) { rbd[base + ii] = bd[ii]; rbk[base + ii] = bk[ii]; }
  }
  __syncthreads();

  if (tid < 128) {
    float d0 = rbd[tid];       int k0 = rbk[tid];
    float d1 = rbd[128 + tid]; int k1 = rbk[128 + tid];
    int kb2 = (d1 < d0 || (d1 == d0 && k1 < k0)) ? k1 : k0;
    skf[tid] = kb2;
    out_idx[(blk << 7) + tid] = (float)kb2;
  }
  __syncthreads();

  // epilogue: z from LDS (bit-same), e gathered from emb, coalesced stores
  int t = tid & 127;
  int ch = tid >> 7;
  int kq = skf[t];
  const float* eq = emb + (size_t)(kq << 6) + (ch << 5);
  float lsum = 0.f;
  float* ob = out_zq + (size_t)b * CHW + s0 + t;
  #pragma unroll
  for (int jj = 0; jj < 32; ++jj) {
    int c = (ch << 5) + jj;
    float zv = zt[(c << 7) + t];
    float e = eq[jj];
    float df = zv - e;
    lsum = fmaf(df, df, lsum);
    ob[(size_t)c * HW] = zv + (e - zv);
  }
  for (int o = 32; o > 0; o >>= 1) lsum += __shfl_down(lsum, o, 64);
  if (lane == 0) sred[wv] = lsum;
  __syncthreads();
  if (tid == 0) loss_part[blk] = sred[0] + sred[1] + sred[2] + sred[3];
}

// ---------------- k_post: histogram + vq_loss + perplexity, one block ----------------
__global__ __launch_bounds__(1024) void k_post(const float* __restrict__ loss_part,
                                               const float* __restrict__ out_idx,
                                               float* __restrict__ out_scalars) {
  __shared__ int hist[1024];
  __shared__ double rl[16], rh[16];
  int tid = threadIdx.x;
  hist[tid] = 0;
  __syncthreads();
  const float2* idx2 = (const float2*)out_idx;   // 8B-aligned base
  #pragma unroll
  for (int jj = 0; jj < 32; ++jj) {
    float2 v = idx2[tid + (jj << 10)];
    atomicAdd(&hist[(int)v.x], 1);
    atomicAdd(&hist[(int)v.y], 1);
  }
  __syncthreads();
  double ls = 0.0;
  if (tid < 512) ls = (double)loss_part[tid];
  float p = (float)hist[tid] * (1.0f / 65536.0f);
  float lg = logf(fmaxf(p, 1e-10f));
  double hs = (double)(p * lg);
  for (int o = 32; o > 0; o >>= 1) {
    ls += __shfl_down(ls, o, 64);
    hs += __shfl_down(hs, o, 64);
  }
  int wv = tid >> 6, ln = tid & 63;
  if (ln == 0) { rl[wv] = ls; rh[wv] = hs; }
  __syncthreads();
  if (tid == 0) {
    double L = 0.0, Hn = 0.0;
    #pragma unroll
    for (int w = 0; w < 16; ++w) { L += rl[w]; Hn += rh[w]; }
    float m = (float)(L / (double)NELEM);
    out_scalars[0] = 0.25f * m + m;
    out_scalars[1] = expf((float)(-Hn));
  }
}

extern "C" void kernel_launch(void* const* d_in, const int* in_sizes, int n_in,
                              void* d_out, int out_size, void* d_ws, size_t ws_size,
                              hipStream_t stream) {
  const float* z_e = (const float*)d_in[0];
  const float* emb = (const float*)d_in[1];
  float* ws = (float*)d_ws;
  float* loss_part = ws + WS_LOSS;
  float* stdv = ws + WS_STD;
  float* eeg = ws + WS_EE;
  float* etg = ws + WS_ETG;     // total ws use ~263 KB

  float* out = (float*)d_out;
  float* out_zq = out;                  // 4194304
  float* out_scalars = out + NELEM;     // vq_loss, perplexity
  float* out_idx = out + NELEM + 2;     // 65536 indices as float

  k_pre<<<80, 1024, 0, stream>>>(z_e, emb, stdv, etg, eeg);
  k_vq<<<512, 256, 0, stream>>>(z_e, emb, stdv, eeg, etg, out_zq, out_idx, loss_part);
  k_post<<<1, 1024, 0, stream>>>(loss_part, out_idx, out_scalars);
}